// Round 13
// baseline (133.284 us; speedup 1.0000x reference)
//
#include <hip/hip_runtime.h>
#include <hip/hip_bf16.h>

typedef short short8 __attribute__((ext_vector_type(8)));
typedef float f32x4 __attribute__((ext_vector_type(4)));
typedef unsigned int uint;

#define CB   16
#define TT   8
#define CIN  1024
#define ICH  512
#define HWS  196
#define NPB  1568   // cols per batch (196*8)
#define NF   25088  // flat cols = 16*1568
#define NXBLK 784   // 16 b x 49 hw-groups (4 hw each)

static __device__ __forceinline__ unsigned short f2bf(float f) {
  __hip_bfloat16 h = __float2bfloat16(f); unsigned short u; __builtin_memcpy(&u, &h, 2); return u;
}

// async global->LDS, 16B per lane; LDS dest is wave-uniform base + lane*16
static __device__ __forceinline__ void stage16(const void* g, void* l) {
  __builtin_amdgcn_global_load_lds(
      (const __attribute__((address_space(1))) unsigned int*)(unsigned long long)g,
      (__attribute__((address_space(3))) unsigned int*)(unsigned int)(unsigned long long)l,
      16, 0, 0);
}

// ---------------- fused prep ----------------
// Transpose blocks [0, NXBLK): block = (b, hw-group of 4), ALL t, ALL c.
//   Output rows n = b*1568 + (hw0+j)*8 + t for j=0..3, t=0..7 are 32 CONSECUTIVE
//   rows -> one 64-KB fully contiguous global write per block.
//   Reads: 8192 aligned float4 (one per (t,c) row at hw0). hw-group-fast XCD
//   swizzle -> the 4 blocks sharing each 64-B read line sit on one XCD (L2 hit).
//   LDS [32 n][1024 c] bf16 (64 KB): load-write bank = c>>1 (2 lanes/bank, free);
//   store-read uint4 4g-pattern (2 lanes/bank, free).
// Weight blocks [NXBLK, NXBLK+2048): unchanged weight prep.
__global__ void k_prep(const float* __restrict__ x, __hip_bfloat16* __restrict__ xbT,
    const float* __restrict__ w1, const float* __restrict__ w2,
    const float* __restrict__ wb1, const float* __restrict__ bb1,
    const float* __restrict__ wb2, const float* __restrict__ bb2,
    const float* __restrict__ wb3, const float* __restrict__ bb3,
    const float* __restrict__ wb4, const float* __restrict__ bb4,
    __hip_bfloat16* __restrict__ w1b, __hip_bfloat16* __restrict__ w2b,
    float* __restrict__ weff, float* __restrict__ beff) {
  int bid = blockIdx.x;
  if (bid >= NXBLK) {
    int idx = (bid - NXBLK) * 256 + threadIdx.x;
    if (idx < CIN * ICH) {
      w1b[idx] = __float2bfloat16(w1[idx]);
      w2b[idx] = __float2bfloat16(w2[idx]);
    }
    if (idx < ICH) {
      float e[7];
#pragma unroll
      for (int u = 0; u < 7; u++) e[u] = wb4[idx * 7 + u];
#pragma unroll
      for (int u = 0; u < 5; u++) e[u + 1] += wb3[idx * 5 + u];
#pragma unroll
      for (int u = 0; u < 3; u++) e[u + 2] += wb2[idx * 3 + u];
      e[3] += wb1[idx];
#pragma unroll
      for (int u = 0; u < 7; u++) weff[idx * 8 + u] = e[u];
      weff[idx * 8 + 7] = 0.f;
      beff[idx] = bb1[idx] + bb2[idx] + bb3[idx] + bb4[idx];
    }
    return;
  }
  // 784 = 8 XCD x 98; hw-group fastest within an XCD chunk
  int xcd = bid & 7, i = bid >> 3;
  int id = xcd * 98 + i;               // bijective (784 % 8 == 0)
  int b = id / 49, hwg = id - b * 49;
  int hw0 = hwg * 4;
  __shared__ unsigned short tile[32 * 1024];  // [n_local][c] bf16, 64 KB
  const float* src = x + (size_t)(b * TT) * CIN * HWS + hw0;
#pragma unroll 4
  for (int it = 0; it < 32; it++) {
    int idx = it * 256 + threadIdx.x;  // t*1024 + c
    f32x4 v = *(const f32x4*)(src + (size_t)idx * HWS);
    int t = idx >> 10, c = idx & 1023;
    tile[(t) * 1024 + c + 0 * 8192] = f2bf(v[0]);   // n_local = j*8 + t
    tile[(t) * 1024 + c + 1 * 8192] = f2bf(v[1]);
    tile[(t) * 1024 + c + 2 * 8192] = f2bf(v[2]);
    tile[(t) * 1024 + c + 3 * 8192] = f2bf(v[3]);
  }
  __syncthreads();
  // 32 consecutive n-rows starting at n0 = b*NPB + hw0*8 -> 64 KB contiguous
  uint4* gdst = (uint4*)(xbT + ((size_t)b * NPB + hw0 * 8) * CIN);
  const uint4* tsrc = (const uint4*)tile;
#pragma unroll 4
  for (int it = 0; it < 16; it++) {
    int idx = it * 256 + threadIdx.x;
    gdst[idx] = tsrc[idx];
  }
}

// ---------------- 256x256 GEMM core, BK=64, 16 waves (4x4), 64x64 per wave ----------------
// (unchanged from R12 — proven best)
template <int KD>
static __device__ __forceinline__ void gemm_core16(
    const __hip_bfloat16* __restrict__ Ar,  // 256 rows x KD (k-contiguous)
    const __hip_bfloat16* __restrict__ Br,  // 256 rows x KD
    __hip_bfloat16* As, __hip_bfloat16* Bs, f32x4 (&acc)[4][4]) {
  constexpr int NT = KD / 64;
  const int tid = threadIdx.x;
  const int lane = tid & 63, w = tid >> 6;   // w 0..15
  const int wm = w >> 2, wn = w & 3;
  const int ln = lane & 15, lm = lane >> 4;
  const int srow = lane >> 3;                 // 0..7 (== row&7)
  const int schk = (lane & 7) ^ srow;
  const __hip_bfloat16* aS = Ar + (size_t)(w * 8 + srow) * KD + schk * 8;
  const __hip_bfloat16* bS = Br + (size_t)(w * 8 + srow) * KD + schk * 8;
  __hip_bfloat16* aD = As + (w * 8) * 64;
  __hip_bfloat16* bD = Bs + (w * 8) * 64;
  const int ck0 = ((lm) ^ (ln & 7)) * 8;
  const int ck1 = ((4 + lm) ^ (ln & 7)) * 8;
  const int rab = (wm * 16 + ln) * 64;  // + mf*4096
  const int rbb = (wn * 64 + ln) * 64;  // + nf*1024

#define STG(src, dst, h, kt, buf) \
  stage16(src + (size_t)((h) * 128) * KD + (kt) * 64, dst + (buf) * 16384 + ((h) * 128) * 64)

  STG(bS, bD, 0, 0, 0); STG(bS, bD, 1, 0, 0);
  STG(aS, aD, 0, 0, 0); STG(aS, aD, 1, 0, 0);

  short8 af0, af1, bfA[4], bfB[4];
  for (int t = 0; t < NT; t++) {
    const int buf = t & 1, nb = buf ^ 1;
    const bool has = (t + 1 < NT);
    const __hip_bfloat16* Ab = As + buf * 16384;
    const __hip_bfloat16* Bb = Bs + buf * 16384;
    // ---- p0: mf0,1 x ck0 ----
    if (has) STG(bS, bD, 0, t + 1, nb);
    if (has) asm volatile("s_waitcnt vmcnt(2)" ::: "memory");
    else     asm volatile("s_waitcnt vmcnt(1)" ::: "memory");
    asm volatile("s_barrier" ::: "memory");
    af0 = *(const short8*)&Ab[rab + ck0];
    af1 = *(const short8*)&Ab[rab + 4096 + ck0];
#pragma unroll
    for (int nf = 0; nf < 4; nf++) bfA[nf] = *(const short8*)&Bb[rbb + nf * 1024 + ck0];
    asm volatile("s_waitcnt lgkmcnt(0)" ::: "memory");
    __builtin_amdgcn_sched_barrier(0);
    __builtin_amdgcn_s_setprio(1);
#pragma unroll
    for (int nf = 0; nf < 4; nf++) {
      acc[0][nf] = __builtin_amdgcn_mfma_f32_16x16x32_bf16(af0, bfA[nf], acc[0][nf], 0, 0, 0);
      acc[1][nf] = __builtin_amdgcn_mfma_f32_16x16x32_bf16(af1, bfA[nf], acc[1][nf], 0, 0, 0);
    }
    __builtin_amdgcn_s_setprio(0);
    // ---- p1: mf0,1 x ck1 ----
    if (has) STG(bS, bD, 1, t + 1, nb);
    af0 = *(const short8*)&Ab[rab + ck1];
    af1 = *(const short8*)&Ab[rab + 4096 + ck1];
#pragma unroll
    for (int nf = 0; nf < 4; nf++) bfB[nf] = *(const short8*)&Bb[rbb + nf * 1024 + ck1];
    asm volatile("s_waitcnt lgkmcnt(0)" ::: "memory");
    __builtin_amdgcn_sched_barrier(0);
    __builtin_amdgcn_s_setprio(1);
#pragma unroll
    for (int nf = 0; nf < 4; nf++) {
      acc[0][nf] = __builtin_amdgcn_mfma_f32_16x16x32_bf16(af0, bfB[nf], acc[0][nf], 0, 0, 0);
      acc[1][nf] = __builtin_amdgcn_mfma_f32_16x16x32_bf16(af1, bfB[nf], acc[1][nf], 0, 0, 0);
    }
    __builtin_amdgcn_s_setprio(0);
    // ---- p2: mf2,3 x ck0 ----
    if (has) STG(aS, aD, 0, t + 1, nb);
    if (has) asm volatile("s_waitcnt vmcnt(3)" ::: "memory");
    else     asm volatile("s_waitcnt vmcnt(0)" ::: "memory");
    asm volatile("s_barrier" ::: "memory");
    af0 = *(const short8*)&Ab[rab + 2 * 4096 + ck0];
    af1 = *(const short8*)&Ab[rab + 3 * 4096 + ck0];
    asm volatile("s_waitcnt lgkmcnt(0)" ::: "memory");
    __builtin_amdgcn_sched_barrier(0);
    __builtin_amdgcn_s_setprio(1);
#pragma unroll
    for (int nf = 0; nf < 4; nf++) {
      acc[2][nf] = __builtin_amdgcn_mfma_f32_16x16x32_bf16(af0, bfA[nf], acc[2][nf], 0, 0, 0);
      acc[3][nf] = __builtin_amdgcn_mfma_f32_16x16x32_bf16(af1, bfA[nf], acc[3][nf], 0, 0, 0);
    }
    __builtin_amdgcn_s_setprio(0);
    // ---- p3: mf2,3 x ck1; end barrier before MFMAs ----
    if (has) STG(aS, aD, 1, t + 1, nb);
    af0 = *(const short8*)&Ab[rab + 2 * 4096 + ck1];
    af1 = *(const short8*)&Ab[rab + 3 * 4096 + ck1];
    asm volatile("s_waitcnt lgkmcnt(0)" ::: "memory");
    __builtin_amdgcn_sched_barrier(0);
    asm volatile("s_barrier" ::: "memory");
    __builtin_amdgcn_s_setprio(1);
#pragma unroll
    for (int nf = 0; nf < 4; nf++) {
      acc[2][nf] = __builtin_amdgcn_mfma_f32_16x16x32_bf16(af0, bfB[nf], acc[2][nf], 0, 0, 0);
      acc[3][nf] = __builtin_amdgcn_mfma_f32_16x16x32_bf16(af1, bfB[nf], acc[3][nf], 0, 0, 0);
    }
    __builtin_amdgcn_s_setprio(0);
  }
#undef STG
}

// ---------------- GEMM1 + fused 7-tap conv epilogue: writes dwT directly ----------------
__global__ __launch_bounds__(1024, 4) void k_gemm1(const __hip_bfloat16* __restrict__ xbT,
                                                   const __hip_bfloat16* __restrict__ w1b,
                                                   const float* __restrict__ b1,
                                                   const float* __restrict__ weff,
                                                   const float* __restrict__ beff,
                                                   __hip_bfloat16* __restrict__ dwT) {
  __shared__ __hip_bfloat16 As[2 * 256 * 64];
  __shared__ __hip_bfloat16 Bs[2 * 256 * 64];
  int xcd = blockIdx.x & 7, i = blockIdx.x >> 3;
  int id = (xcd < 4 ? xcd * 25 : 100 + (xcd - 4) * 24) + i;
  int rt = id >> 1, ot = id & 1;
  int n0 = rt * 256, o0 = ot * 256;
  f32x4 acc[4][4];
#pragma unroll
  for (int a = 0; a < 4; a++)
#pragma unroll
    for (int c = 0; c < 4; c++) acc[a][c] = (f32x4){0.f, 0.f, 0.f, 0.f};
  gemm_core16<1024>(xbT + (size_t)n0 * CIN, w1b + (size_t)o0 * CIN, As, Bs, acc);

  int tid = threadIdx.x, lane = tid & 63, w = tid >> 6;
  int wm = w >> 2, wn = w & 3, ln = lane & 15, lm = lane >> 4;
  bool hiT = (lm & 1);
#pragma unroll
  for (int nf = 0; nf < 4; nf++) {
    int o = o0 + wn * 64 + nf * 16 + ln;
    float e[7];
#pragma unroll
    for (int u = 0; u < 7; u++) e[u] = weff[o * 8 + u];
    float be = beff[o];
    float bo = b1[o];
#pragma unroll
    for (int mf = 0; mf < 4; mf++) {
      float av[4], pv[4];
#pragma unroll
      for (int j = 0; j < 4; j++) av[j] = acc[mf][nf][j] + bo;
#pragma unroll
      for (int j = 0; j < 4; j++) pv[j] = __shfl_xor(av[j], 16, 64);
      float ov[4];
      if (hiT) {
#pragma unroll
        for (int j = 0; j < 4; j++) {
          float s = be;
#pragma unroll
          for (int u = 0; u < 7; u++) {
            int ss = 4 + j + u - 3;
            if (ss >= 0 && ss < 8) s += e[u] * (ss < 4 ? pv[ss] : av[ss - 4]);
          }
          ov[j] = s;
        }
      } else {
#pragma unroll
        for (int j = 0; j < 4; j++) {
          float s = be;
#pragma unroll
          for (int u = 0; u < 7; u++) {
            int ss = j + u - 3;
            if (ss >= 0 && ss < 8) s += e[u] * (ss < 4 ? av[ss] : pv[ss - 4]);
          }
          ov[j] = s;
        }
      }
      int grow = n0 + mf * 64 + wm * 16 + ((lm >> 1) & 1) * 8;
      int gidx = grow >> 3;  // = b*196 + hw
      int gb = gidx / HWS, ghw = gidx - gb * HWS;
      int tb = hiT ? 4 : 0;
#pragma unroll
      for (int j = 0; j < 4; j++) {
        size_t rr = (size_t)gb * NPB + (size_t)(tb + j) * HWS + ghw;
        dwT[rr * ICH + o] = __float2bfloat16(ov[j]);
      }
    }
  }
}

// ---------------- GEMM2: out = w2b . dwT + b2 + residual; bounced float4 epilogue ----------------
__global__ __launch_bounds__(1024, 4) void k_gemm2(const __hip_bfloat16* __restrict__ dwT,
                                                   const __hip_bfloat16* __restrict__ w2b,
                                                   const float* __restrict__ b2,
                                                   const float* __restrict__ xres,
                                                   float* __restrict__ out) {
  __shared__ __align__(16) char smem[131072];
  __hip_bfloat16* As = (__hip_bfloat16*)smem;
  __hip_bfloat16* Bs = (__hip_bfloat16*)(smem + 65536);
  int id = (blockIdx.x & 7) * 49 + (blockIdx.x >> 3);
  int nt = id >> 2, mt = id & 3;
  int n0 = nt * 256, m0 = mt * 256;
  f32x4 acc[4][4];
#pragma unroll
  for (int a = 0; a < 4; a++)
#pragma unroll
    for (int c = 0; c < 4; c++) acc[a][c] = (f32x4){0.f, 0.f, 0.f, 0.f};
  gemm_core16<512>(w2b + (size_t)m0 * ICH, dwT + (size_t)n0 * ICH, As, Bs, acc);

  int tid = threadIdx.x, lane = tid & 63, w = tid >> 6;
  int wm = w >> 2, wn = w & 3, ln = lane & 15, lm = lane >> 4;
  float* arr = (float*)smem;  // bounce: [64 o2-rows][260 cols] fp32 per pass
  int fc = tid & 63, fr = tid >> 6;  // fr 0..15, wave-uniform
  int n2 = n0 + fc * 4;
  int bb = n2 / NPB, r = n2 - bb * NPB;
  int t2 = r / HWS, hw = r - t2 * HWS;
  size_t base4 = ((size_t)((bb * TT + t2) * CIN)) * HWS + hw;
#pragma unroll
  for (int p = 0; p < 4; p++) {
    __syncthreads();
#pragma unroll
    for (int nf = 0; nf < 4; nf++)
#pragma unroll
      for (int j = 0; j < 4; j++)
        arr[(wm * 16 + lm * 4 + j) * 260 + wn * 64 + nf * 16 + ln] = acc[p][nf][j];
    __syncthreads();
#pragma unroll
    for (int it = 0; it < 4; it++) {
      int o2l = it * 16 + fr;
      f32x4 v = *(const f32x4*)&arr[o2l * 260 + fc * 4];
      int o2 = m0 + p * 64 + o2l;
      float bo = b2[o2];
      size_t a = base4 + (size_t)o2 * HWS;
      float4 xr = *(const float4*)(xres + a);
      float4 ov = make_float4(v[0] + bo + xr.x, v[1] + bo + xr.y,
                              v[2] + bo + xr.z, v[3] + bo + xr.w);
      *(float4*)(out + a) = ov;
    }
  }
}

extern "C" void kernel_launch(void* const* d_in, const int* in_sizes, int n_in,
                              void* d_out, int out_size, void* d_ws, size_t ws_size,
                              hipStream_t stream) {
  const float* x   = (const float*)d_in[0];
  const float* w1  = (const float*)d_in[1];
  const float* b1  = (const float*)d_in[2];
  const float* wb1 = (const float*)d_in[3];
  const float* bb1 = (const float*)d_in[4];
  const float* wb2 = (const float*)d_in[5];
  const float* bb2 = (const float*)d_in[6];
  const float* wb3 = (const float*)d_in[7];
  const float* bb3 = (const float*)d_in[8];
  const float* wb4 = (const float*)d_in[9];
  const float* bb4 = (const float*)d_in[10];
  const float* w2  = (const float*)d_in[11];
  const float* b2  = (const float*)d_in[12];
  float* out = (float*)d_out;

  // d_out as scratch: xbT bf16 [NF][CIN] at offset 0 (51.4MB; dead before gemm2 writes out)
  __hip_bfloat16* xbT = (__hip_bfloat16*)d_out;

  // ws: dwT 25.69MB + w1b 1MB + w2b 1MB + weff 16KB + beff 2KB
  char* ws = (char*)d_ws;
  __hip_bfloat16* dwT = (__hip_bfloat16*)ws;
  __hip_bfloat16* w1b = (__hip_bfloat16*)(ws + 25690112);
  __hip_bfloat16* w2b = (__hip_bfloat16*)(ws + 25690112 + 1048576);
  float* weff = (float*)(ws + 25690112 + 2097152);
  float* beff = weff + 4096;

  k_prep<<<NXBLK + (CIN * ICH + 255) / 256, 256, 0, stream>>>(
      x, xbT, w1, w2, wb1, bb1, wb2, bb2, wb3, bb3, wb4, bb4, w1b, w2b, weff, beff);
  k_gemm1<<<196, 1024, 0, stream>>>(xbT, w1b, b1, weff, beff, dwT);
  k_gemm2<<<392, 1024, 0, stream>>>(dwT, w2b, b2, x, out);
}

// Round 14
// 117.263 us; speedup vs baseline: 1.1366x; 1.1366x over previous
//
#include <hip/hip_runtime.h>
#include <hip/hip_bf16.h>

typedef short short8 __attribute__((ext_vector_type(8)));
typedef float f32x4 __attribute__((ext_vector_type(4)));
typedef unsigned int uint;

#define CB   16
#define TT   8
#define CIN  1024
#define ICH  512
#define HWS  196
#define NPB  1568   // cols per batch (196*8)
#define NF   25088  // flat cols = 16*1568

static __device__ __forceinline__ unsigned short f2bf(float f) {
  __hip_bfloat16 h = __float2bfloat16(f); unsigned short u; __builtin_memcpy(&u, &h, 2); return u;
}

// async global->LDS, 16B per lane; LDS dest is wave-uniform base + lane*16
static __device__ __forceinline__ void stage16(const void* g, void* l) {
  __builtin_amdgcn_global_load_lds(
      (const __attribute__((address_space(1))) unsigned int*)(unsigned long long)g,
      (__attribute__((address_space(3))) unsigned int*)(unsigned int)(unsigned long long)l,
      16, 0, 0);
}

// ---------------- weight prep (256 thr) ----------------
__global__ void k_prep_w(const float* __restrict__ w1, const float* __restrict__ w2,
    const float* __restrict__ wb1, const float* __restrict__ bb1,
    const float* __restrict__ wb2, const float* __restrict__ bb2,
    const float* __restrict__ wb3, const float* __restrict__ bb3,
    const float* __restrict__ wb4, const float* __restrict__ bb4,
    __hip_bfloat16* __restrict__ w1b, __hip_bfloat16* __restrict__ w2b,
    float* __restrict__ weff, float* __restrict__ beff) {
  int idx = blockIdx.x * 256 + threadIdx.x;
  if (idx < CIN * ICH) {
    w1b[idx] = __float2bfloat16(w1[idx]);
    w2b[idx] = __float2bfloat16(w2[idx]);
  }
  if (idx < ICH) {
    float e[7];
#pragma unroll
    for (int u = 0; u < 7; u++) e[u] = wb4[idx * 7 + u];
#pragma unroll
    for (int u = 0; u < 5; u++) e[u + 1] += wb3[idx * 5 + u];
#pragma unroll
    for (int u = 0; u < 3; u++) e[u + 2] += wb2[idx * 3 + u];
    e[3] += wb1[idx];
#pragma unroll
    for (int u = 0; u < 7; u++) weff[idx * 8 + u] = e[u];
    weff[idx * 8 + 7] = 0.f;
    beff[idx] = bb1[idx] + bb2[idx] + bb3[idx] + bb4[idx];
  }
}

// ---------------- x transpose v3 (448 thr, 1024 blocks) ----------------
// Block = (bt, cr of 128 c). Read: [c0..c0+128)x[0..196) is ONE contiguous
// 100,352-B run (49 float4 per row exactly) -> perfectly coalesced idx*16.
// LDS [hw][128 c] bf16 with chunk-XOR: element c of row hw stored at chunk
// slot (c>>3) ^ ((hw + (hw>>2)) & 15)  (Δhwq generates all 16 slots, gcd(5,16)=1
// -> scattered b16 writes spread over all banks, ~2-way = free). Write phase
// inverts the same involution, reads b128 (free), stores 256-B runs per output
// row; cr-siblings adjacent on one XCD so L2 merges segments of each 2-KB row.
__global__ __launch_bounds__(448) void k_prep_x(const float* __restrict__ x,
                                                __hip_bfloat16* __restrict__ xbT) {
  __shared__ unsigned short tile[196 * 128];  // 50176 B
  int xcd = blockIdx.x & 7, i = blockIdx.x >> 3;
  int id = xcd * 128 + i;          // bijective (1024 % 8 == 0); cr fastest
  int bt = id >> 3, cr = id & 7;
  int c0 = cr * 128;
  int b = bt >> 3, t = bt & 7;
  const float* src = x + ((size_t)bt * CIN + c0) * HWS;
  int tid = threadIdx.x;
#pragma unroll
  for (int it = 0; it < 14; it++) {
    int idx = it * 448 + tid;               // = c*49 + hwq
    f32x4 v = *(const f32x4*)(src + (size_t)idx * 4);
    int c = idx / 49, hwq = idx - c * 49;
#pragma unroll
    for (int j = 0; j < 4; j++) {
      int hw = hwq * 4 + j;
      int slot = (c >> 3) ^ ((hw + (hw >> 2)) & 15);
      tile[hw * 128 + slot * 8 + (c & 7)] = f2bf(v[j]);
    }
  }
  __syncthreads();
  __hip_bfloat16* dstb = xbT + ((size_t)b * NPB + (size_t)t) * CIN + c0;
#pragma unroll
  for (int it = 0; it < 7; it++) {
    int idx = it * 448 + tid;               // = hw*16 + co
    int hw = idx >> 4, co = idx & 15;
    int slot = co ^ ((hw + (hw >> 2)) & 15);
    uint4 val = *(const uint4*)&tile[hw * 128 + slot * 8];
    *(uint4*)(dstb + (size_t)(hw * 8) * CIN + co * 8) = val;
  }
}

// ---------------- 256x256 GEMM core, BK=64, 16 waves (4x4), 64x64 per wave ----------------
// (unchanged from R12 — proven best)
template <int KD>
static __device__ __forceinline__ void gemm_core16(
    const __hip_bfloat16* __restrict__ Ar,  // 256 rows x KD (k-contiguous)
    const __hip_bfloat16* __restrict__ Br,  // 256 rows x KD
    __hip_bfloat16* As, __hip_bfloat16* Bs, f32x4 (&acc)[4][4]) {
  constexpr int NT = KD / 64;
  const int tid = threadIdx.x;
  const int lane = tid & 63, w = tid >> 6;   // w 0..15
  const int wm = w >> 2, wn = w & 3;
  const int ln = lane & 15, lm = lane >> 4;
  const int srow = lane >> 3;                 // 0..7 (== row&7)
  const int schk = (lane & 7) ^ srow;
  const __hip_bfloat16* aS = Ar + (size_t)(w * 8 + srow) * KD + schk * 8;
  const __hip_bfloat16* bS = Br + (size_t)(w * 8 + srow) * KD + schk * 8;
  __hip_bfloat16* aD = As + (w * 8) * 64;
  __hip_bfloat16* bD = Bs + (w * 8) * 64;
  const int ck0 = ((lm) ^ (ln & 7)) * 8;
  const int ck1 = ((4 + lm) ^ (ln & 7)) * 8;
  const int rab = (wm * 16 + ln) * 64;  // + mf*4096
  const int rbb = (wn * 64 + ln) * 64;  // + nf*1024

#define STG(src, dst, h, kt, buf) \
  stage16(src + (size_t)((h) * 128) * KD + (kt) * 64, dst + (buf) * 16384 + ((h) * 128) * 64)

  STG(bS, bD, 0, 0, 0); STG(bS, bD, 1, 0, 0);
  STG(aS, aD, 0, 0, 0); STG(aS, aD, 1, 0, 0);

  short8 af0, af1, bfA[4], bfB[4];
  for (int t = 0; t < NT; t++) {
    const int buf = t & 1, nb = buf ^ 1;
    const bool has = (t + 1 < NT);
    const __hip_bfloat16* Ab = As + buf * 16384;
    const __hip_bfloat16* Bb = Bs + buf * 16384;
    // ---- p0: mf0,1 x ck0 ----
    if (has) STG(bS, bD, 0, t + 1, nb);
    if (has) asm volatile("s_waitcnt vmcnt(2)" ::: "memory");
    else     asm volatile("s_waitcnt vmcnt(1)" ::: "memory");
    asm volatile("s_barrier" ::: "memory");
    af0 = *(const short8*)&Ab[rab + ck0];
    af1 = *(const short8*)&Ab[rab + 4096 + ck0];
#pragma unroll
    for (int nf = 0; nf < 4; nf++) bfA[nf] = *(const short8*)&Bb[rbb + nf * 1024 + ck0];
    asm volatile("s_waitcnt lgkmcnt(0)" ::: "memory");
    __builtin_amdgcn_sched_barrier(0);
    __builtin_amdgcn_s_setprio(1);
#pragma unroll
    for (int nf = 0; nf < 4; nf++) {
      acc[0][nf] = __builtin_amdgcn_mfma_f32_16x16x32_bf16(af0, bfA[nf], acc[0][nf], 0, 0, 0);
      acc[1][nf] = __builtin_amdgcn_mfma_f32_16x16x32_bf16(af1, bfA[nf], acc[1][nf], 0, 0, 0);
    }
    __builtin_amdgcn_s_setprio(0);
    // ---- p1: mf0,1 x ck1 ----
    if (has) STG(bS, bD, 1, t + 1, nb);
    af0 = *(const short8*)&Ab[rab + ck1];
    af1 = *(const short8*)&Ab[rab + 4096 + ck1];
#pragma unroll
    for (int nf = 0; nf < 4; nf++) bfB[nf] = *(const short8*)&Bb[rbb + nf * 1024 + ck1];
    asm volatile("s_waitcnt lgkmcnt(0)" ::: "memory");
    __builtin_amdgcn_sched_barrier(0);
    __builtin_amdgcn_s_setprio(1);
#pragma unroll
    for (int nf = 0; nf < 4; nf++) {
      acc[0][nf] = __builtin_amdgcn_mfma_f32_16x16x32_bf16(af0, bfB[nf], acc[0][nf], 0, 0, 0);
      acc[1][nf] = __builtin_amdgcn_mfma_f32_16x16x32_bf16(af1, bfB[nf], acc[1][nf], 0, 0, 0);
    }
    __builtin_amdgcn_s_setprio(0);
    // ---- p2: mf2,3 x ck0 ----
    if (has) STG(aS, aD, 0, t + 1, nb);
    if (has) asm volatile("s_waitcnt vmcnt(3)" ::: "memory");
    else     asm volatile("s_waitcnt vmcnt(0)" ::: "memory");
    asm volatile("s_barrier" ::: "memory");
    af0 = *(const short8*)&Ab[rab + 2 * 4096 + ck0];
    af1 = *(const short8*)&Ab[rab + 3 * 4096 + ck0];
    asm volatile("s_waitcnt lgkmcnt(0)" ::: "memory");
    __builtin_amdgcn_sched_barrier(0);
    __builtin_amdgcn_s_setprio(1);
#pragma unroll
    for (int nf = 0; nf < 4; nf++) {
      acc[2][nf] = __builtin_amdgcn_mfma_f32_16x16x32_bf16(af0, bfA[nf], acc[2][nf], 0, 0, 0);
      acc[3][nf] = __builtin_amdgcn_mfma_f32_16x16x32_bf16(af1, bfA[nf], acc[3][nf], 0, 0, 0);
    }
    __builtin_amdgcn_s_setprio(0);
    // ---- p3: mf2,3 x ck1; end barrier before MFMAs ----
    if (has) STG(aS, aD, 1, t + 1, nb);
    af0 = *(const short8*)&Ab[rab + 2 * 4096 + ck1];
    af1 = *(const short8*)&Ab[rab + 3 * 4096 + ck1];
    asm volatile("s_waitcnt lgkmcnt(0)" ::: "memory");
    __builtin_amdgcn_sched_barrier(0);
    asm volatile("s_barrier" ::: "memory");
    __builtin_amdgcn_s_setprio(1);
#pragma unroll
    for (int nf = 0; nf < 4; nf++) {
      acc[2][nf] = __builtin_amdgcn_mfma_f32_16x16x32_bf16(af0, bfB[nf], acc[2][nf], 0, 0, 0);
      acc[3][nf] = __builtin_amdgcn_mfma_f32_16x16x32_bf16(af1, bfB[nf], acc[3][nf], 0, 0, 0);
    }
    __builtin_amdgcn_s_setprio(0);
  }
#undef STG
}

// ---------------- GEMM1 + fused 7-tap conv epilogue: writes dwT directly ----------------
__global__ __launch_bounds__(1024, 4) void k_gemm1(const __hip_bfloat16* __restrict__ xbT,
                                                   const __hip_bfloat16* __restrict__ w1b,
                                                   const float* __restrict__ b1,
                                                   const float* __restrict__ weff,
                                                   const float* __restrict__ beff,
                                                   __hip_bfloat16* __restrict__ dwT) {
  __shared__ __hip_bfloat16 As[2 * 256 * 64];
  __shared__ __hip_bfloat16 Bs[2 * 256 * 64];
  int xcd = blockIdx.x & 7, i = blockIdx.x >> 3;
  int id = (xcd < 4 ? xcd * 25 : 100 + (xcd - 4) * 24) + i;
  int rt = id >> 1, ot = id & 1;
  int n0 = rt * 256, o0 = ot * 256;
  f32x4 acc[4][4];
#pragma unroll
  for (int a = 0; a < 4; a++)
#pragma unroll
    for (int c = 0; c < 4; c++) acc[a][c] = (f32x4){0.f, 0.f, 0.f, 0.f};
  gemm_core16<1024>(xbT + (size_t)n0 * CIN, w1b + (size_t)o0 * CIN, As, Bs, acc);

  int tid = threadIdx.x, lane = tid & 63, w = tid >> 6;
  int wm = w >> 2, wn = w & 3, ln = lane & 15, lm = lane >> 4;
  bool hiT = (lm & 1);
#pragma unroll
  for (int nf = 0; nf < 4; nf++) {
    int o = o0 + wn * 64 + nf * 16 + ln;
    float e[7];
#pragma unroll
    for (int u = 0; u < 7; u++) e[u] = weff[o * 8 + u];
    float be = beff[o];
    float bo = b1[o];
#pragma unroll
    for (int mf = 0; mf < 4; mf++) {
      float av[4], pv[4];
#pragma unroll
      for (int j = 0; j < 4; j++) av[j] = acc[mf][nf][j] + bo;
#pragma unroll
      for (int j = 0; j < 4; j++) pv[j] = __shfl_xor(av[j], 16, 64);
      float ov[4];
      if (hiT) {
#pragma unroll
        for (int j = 0; j < 4; j++) {
          float s = be;
#pragma unroll
          for (int u = 0; u < 7; u++) {
            int ss = 4 + j + u - 3;
            if (ss >= 0 && ss < 8) s += e[u] * (ss < 4 ? pv[ss] : av[ss - 4]);
          }
          ov[j] = s;
        }
      } else {
#pragma unroll
        for (int j = 0; j < 4; j++) {
          float s = be;
#pragma unroll
          for (int u = 0; u < 7; u++) {
            int ss = j + u - 3;
            if (ss >= 0 && ss < 8) s += e[u] * (ss < 4 ? av[ss] : pv[ss - 4]);
          }
          ov[j] = s;
        }
      }
      int grow = n0 + mf * 64 + wm * 16 + ((lm >> 1) & 1) * 8;
      int gidx = grow >> 3;  // = b*196 + hw
      int gb = gidx / HWS, ghw = gidx - gb * HWS;
      int tb = hiT ? 4 : 0;
#pragma unroll
      for (int j = 0; j < 4; j++) {
        size_t rr = (size_t)gb * NPB + (size_t)(tb + j) * HWS + ghw;
        dwT[rr * ICH + o] = __float2bfloat16(ov[j]);
      }
    }
  }
}

// ---------------- GEMM2: out = w2b . dwT + b2 + residual; bounced float4 epilogue ----------------
__global__ __launch_bounds__(1024, 4) void k_gemm2(const __hip_bfloat16* __restrict__ dwT,
                                                   const __hip_bfloat16* __restrict__ w2b,
                                                   const float* __restrict__ b2,
                                                   const float* __restrict__ xres,
                                                   float* __restrict__ out) {
  __shared__ __align__(16) char smem[131072];
  __hip_bfloat16* As = (__hip_bfloat16*)smem;
  __hip_bfloat16* Bs = (__hip_bfloat16*)(smem + 65536);
  int id = (blockIdx.x & 7) * 49 + (blockIdx.x >> 3);
  int nt = id >> 2, mt = id & 3;
  int n0 = nt * 256, m0 = mt * 256;
  f32x4 acc[4][4];
#pragma unroll
  for (int a = 0; a < 4; a++)
#pragma unroll
    for (int c = 0; c < 4; c++) acc[a][c] = (f32x4){0.f, 0.f, 0.f, 0.f};
  gemm_core16<512>(w2b + (size_t)m0 * ICH, dwT + (size_t)n0 * ICH, As, Bs, acc);

  int tid = threadIdx.x, lane = tid & 63, w = tid >> 6;
  int wm = w >> 2, wn = w & 3, ln = lane & 15, lm = lane >> 4;
  float* arr = (float*)smem;  // bounce: [64 o2-rows][260 cols] fp32 per pass
  int fc = tid & 63, fr = tid >> 6;  // fr 0..15, wave-uniform
  int n2 = n0 + fc * 4;
  int bb = n2 / NPB, r = n2 - bb * NPB;
  int t2 = r / HWS, hw = r - t2 * HWS;
  size_t base4 = ((size_t)((bb * TT + t2) * CIN)) * HWS + hw;
#pragma unroll
  for (int p = 0; p < 4; p++) {
    __syncthreads();
#pragma unroll
    for (int nf = 0; nf < 4; nf++)
#pragma unroll
      for (int j = 0; j < 4; j++)
        arr[(wm * 16 + lm * 4 + j) * 260 + wn * 64 + nf * 16 + ln] = acc[p][nf][j];
    __syncthreads();
#pragma unroll
    for (int it = 0; it < 4; it++) {
      int o2l = it * 16 + fr;
      f32x4 v = *(const f32x4*)&arr[o2l * 260 + fc * 4];
      int o2 = m0 + p * 64 + o2l;
      float bo = b2[o2];
      size_t a = base4 + (size_t)o2 * HWS;
      float4 xr = *(const float4*)(xres + a);
      float4 ov = make_float4(v[0] + bo + xr.x, v[1] + bo + xr.y,
                              v[2] + bo + xr.z, v[3] + bo + xr.w);
      *(float4*)(out + a) = ov;
    }
  }
}

extern "C" void kernel_launch(void* const* d_in, const int* in_sizes, int n_in,
                              void* d_out, int out_size, void* d_ws, size_t ws_size,
                              hipStream_t stream) {
  const float* x   = (const float*)d_in[0];
  const float* w1  = (const float*)d_in[1];
  const float* b1  = (const float*)d_in[2];
  const float* wb1 = (const float*)d_in[3];
  const float* bb1 = (const float*)d_in[4];
  const float* wb2 = (const float*)d_in[5];
  const float* bb2 = (const float*)d_in[6];
  const float* wb3 = (const float*)d_in[7];
  const float* bb3 = (const float*)d_in[8];
  const float* wb4 = (const float*)d_in[9];
  const float* bb4 = (const float*)d_in[10];
  const float* w2  = (const float*)d_in[11];
  const float* b2  = (const float*)d_in[12];
  float* out = (float*)d_out;

  // d_out as scratch: xbT bf16 [NF][CIN] at offset 0 (51.4MB; dead before gemm2 writes out)
  __hip_bfloat16* xbT = (__hip_bfloat16*)d_out;

  // ws: dwT 25.69MB + w1b 1MB + w2b 1MB + weff 16KB + beff 2KB
  char* ws = (char*)d_ws;
  __hip_bfloat16* dwT = (__hip_bfloat16*)ws;
  __hip_bfloat16* w1b = (__hip_bfloat16*)(ws + 25690112);
  __hip_bfloat16* w2b = (__hip_bfloat16*)(ws + 25690112 + 1048576);
  float* weff = (float*)(ws + 25690112 + 2097152);
  float* beff = weff + 4096;

  k_prep_w<<<(CIN * ICH + 255) / 256, 256, 0, stream>>>(
      w1, w2, wb1, bb1, wb2, bb2, wb3, bb3, wb4, bb4, w1b, w2b, weff, beff);
  k_prep_x<<<1024, 448, 0, stream>>>(x, xbT);
  k_gemm1<<<196, 1024, 0, stream>>>(xbT, w1b, b1, weff, beff, dwT);
  k_gemm2<<<392, 1024, 0, stream>>>(dwT, w2b, b2, x, out);
}